// Round 1
// baseline (2606.360 us; speedup 1.0000x reference)
//
#include <hip/hip_runtime.h>
#include <math.h>

// ---------------- CSR build ----------------

__global__ __launch_bounds__(256) void hist_kernel(const int* __restrict__ dst,
                                                   int* __restrict__ counts, int E) {
  int e = blockIdx.x * 256 + threadIdx.x;
  if (e < E) atomicAdd(&counts[dst[e]], 1);
}

__global__ __launch_bounds__(1024) void scan_kernel(const int* __restrict__ counts,
                                                    int* __restrict__ offs, int n) {
  __shared__ int sd[1024];
  __shared__ int carry_s;
  int tid = threadIdx.x;
  if (tid == 0) carry_s = 0;
  __syncthreads();
  for (int base = 0; base < n; base += 1024) {
    int i = base + tid;
    int v = (i < n) ? counts[i] : 0;
    sd[tid] = v;
    __syncthreads();
    #pragma unroll
    for (int off = 1; off < 1024; off <<= 1) {
      int t = (tid >= off) ? sd[tid - off] : 0;
      __syncthreads();
      sd[tid] += t;
      __syncthreads();
    }
    int incl = sd[tid];
    int carry = carry_s;
    __syncthreads();
    if (i < n) offs[i] = carry + incl - v;   // exclusive
    if (tid == 1023) carry_s = carry + incl;
    __syncthreads();
  }
  if (tid == 0) offs[n] = carry_s;
}

__global__ __launch_bounds__(256) void fill_kernel(const int* __restrict__ src,
                                                   const int* __restrict__ dst,
                                                   const int* __restrict__ offs,
                                                   int* __restrict__ cursor,
                                                   int* __restrict__ csr_src, int E) {
  int e = blockIdx.x * 256 + threadIdx.x;
  if (e < E) {
    int d = dst[e];
    int pos = atomicAdd(&cursor[d], 1);
    csr_src[offs[d] + pos] = src[e];
  }
}

// ---------------- GEMM: Y[nrows,COUT] = X[nrows,128] @ W[128,COUT] + bias ----------------

template <int COUT>
__global__ __launch_bounds__(256) void gemm_kernel(const float* __restrict__ X,
                                                   const float* __restrict__ W,
                                                   const float* __restrict__ bias,
                                                   float* __restrict__ Y, int nrows) {
  constexpr int CG = COUT / 4;    // col groups (4 cols each)
  constexpr int RG = 256 / CG;    // row groups
  constexpr int BM = RG * 4;      // rows per block
  __shared__ float xs[BM][132];   // +4 pad: breaks bank aliasing, keeps 16B alignment
  int tid = threadIdx.x;
  int block_row = blockIdx.x * BM;
  for (int i = tid; i < BM * 32; i += 256) {
    int r = i >> 5, c4 = i & 31;
    int gr = block_row + r;
    float4 v = make_float4(0.f, 0.f, 0.f, 0.f);
    if (gr < nrows) v = reinterpret_cast<const float4*>(X + (size_t)gr * 128)[c4];
    *reinterpret_cast<float4*>(&xs[r][c4 * 4]) = v;
  }
  __syncthreads();
  int c0 = (tid % CG) * 4;
  int r0 = (tid / CG) * 4;
  float acc[4][4] = {};
  for (int k = 0; k < 128; k += 4) {
    float4 xv[4];
    #pragma unroll
    for (int i = 0; i < 4; ++i) xv[i] = *reinterpret_cast<const float4*>(&xs[r0 + i][k]);
    #pragma unroll
    for (int kk = 0; kk < 4; ++kk) {
      float4 w = *reinterpret_cast<const float4*>(&W[(k + kk) * COUT + c0]);
      #pragma unroll
      for (int i = 0; i < 4; ++i) {
        float x = (kk == 0) ? xv[i].x : (kk == 1) ? xv[i].y : (kk == 2) ? xv[i].z : xv[i].w;
        acc[i][0] = fmaf(x, w.x, acc[i][0]);
        acc[i][1] = fmaf(x, w.y, acc[i][1]);
        acc[i][2] = fmaf(x, w.z, acc[i][2]);
        acc[i][3] = fmaf(x, w.w, acc[i][3]);
      }
    }
  }
  float4 bv = *reinterpret_cast<const float4*>(&bias[c0]);
  #pragma unroll
  for (int i = 0; i < 4; ++i) {
    int gr = block_row + r0 + i;
    if (gr < nrows) {
      float4 o;
      o.x = acc[i][0] + bv.x; o.y = acc[i][1] + bv.y;
      o.z = acc[i][2] + bv.z; o.w = acc[i][3] + bv.w;
      *reinterpret_cast<float4*>(&Y[(size_t)gr * COUT + c0]) = o;
    }
  }
}

// ---------------- Aggregate (CSR gather-sum) + BN(inference) + relu ----------------

template <int C>
__global__ __launch_bounds__(256) void agg_kernel(const float* __restrict__ h,
                                                  const int* __restrict__ offs,
                                                  const int* __restrict__ csr_src,
                                                  const float* __restrict__ gamma,
                                                  const float* __restrict__ beta,
                                                  float* __restrict__ out, int n) {
  int node = blockIdx.x * 4 + (threadIdx.x >> 6);  // one wave per node
  if (node >= n) return;
  int lane = threadIdx.x & 63;
  int beg = offs[node], end = offs[node + 1];
  float a0 = 0.f, a1 = 0.f;
  for (int i = beg; i < end; ++i) {
    const float* row = h + (size_t)csr_src[i] * C;
    a0 += row[lane];
    if (C == 128) a1 += row[64 + lane];
  }
  const float inv = 1.0f / sqrtf(1.0f + 1.0e-3f);
  out[(size_t)node * C + lane] = fmaxf(fmaf(a0, gamma[lane] * inv, beta[lane]), 0.f);
  if (C == 128)
    out[(size_t)node * C + 64 + lane] =
        fmaxf(fmaf(a1, gamma[64 + lane] * inv, beta[64 + lane]), 0.f);
}

// ---------------- Segment mean pool (seg sorted): p[64,64] ----------------

__global__ __launch_bounds__(256) void pool_kernel(const float* __restrict__ h,
                                                   const int* __restrict__ seg,
                                                   float* __restrict__ p, int n) {
  int g = blockIdx.x;  // 0..63
  int lo, hi;
  { int l = 0, r = n; while (l < r) { int m = (l + r) >> 1; if (seg[m] < g) l = m + 1; else r = m; } lo = l; }
  { int l = 0, r = n; while (l < r) { int m = (l + r) >> 1; if (seg[m] < g + 1) l = m + 1; else r = m; } hi = l; }
  int c = threadIdx.x & 63;
  int sub = threadIdx.x >> 6;
  float acc = 0.f;
  for (int i = lo + sub; i < hi; i += 4) acc += h[(size_t)i * 64 + c];
  __shared__ float red[4][64];
  red[sub][c] = acc;
  __syncthreads();
  if (sub == 0) {
    float s = red[0][c] + red[1][c] + red[2][c] + red[3][c];
    float cnt = (float)(hi - lo);
    p[g * 64 + c] = s / fmaxf(cnt, 1.0f);
  }
}

// ---------------- Head: concat -> 2x Dense(128,relu, shared W) -> sigmoid ----------------

__global__ __launch_bounds__(512) void head_kernel(const float* __restrict__ p,
                                                   const float* __restrict__ Wd,
                                                   const float* __restrict__ bd,
                                                   const float* __restrict__ Wo,
                                                   const float* __restrict__ bo,
                                                   float* __restrict__ out) {
  __shared__ float cur[64][128];
  __shared__ float nxt[64][128];
  int tid = threadIdx.x;
  const float* p1 = p;
  const float* p2 = p + 64 * 64;
  for (int i = tid; i < 64 * 128; i += 512) {
    int r = i >> 7, c = i & 127;
    cur[r][c] = (c < 64) ? p1[r * 64 + c] : p2[r * 64 + (c - 64)];
  }
  __syncthreads();
  int c0 = (tid & 31) * 4;
  int r0 = (tid >> 5) * 4;
  for (int layer = 0; layer < 2; ++layer) {
    float acc[4][4] = {};
    for (int k = 0; k < 128; ++k) {
      float4 w = *reinterpret_cast<const float4*>(&Wd[k * 128 + c0]);
      #pragma unroll
      for (int i = 0; i < 4; ++i) {
        float x = cur[r0 + i][k];
        acc[i][0] = fmaf(x, w.x, acc[i][0]);
        acc[i][1] = fmaf(x, w.y, acc[i][1]);
        acc[i][2] = fmaf(x, w.z, acc[i][2]);
        acc[i][3] = fmaf(x, w.w, acc[i][3]);
      }
    }
    float4 bv = *reinterpret_cast<const float4*>(&bd[c0]);
    __syncthreads();
    #pragma unroll
    for (int i = 0; i < 4; ++i) {
      float4 o;
      o.x = fmaxf(acc[i][0] + bv.x, 0.f);
      o.y = fmaxf(acc[i][1] + bv.y, 0.f);
      o.z = fmaxf(acc[i][2] + bv.z, 0.f);
      o.w = fmaxf(acc[i][3] + bv.w, 0.f);
      *reinterpret_cast<float4*>(&nxt[r0 + i][c0]) = o;
    }
    __syncthreads();
    for (int i = tid; i < 64 * 128; i += 512) (&cur[0][0])[i] = (&nxt[0][0])[i];
    __syncthreads();
  }
  int wv = tid >> 6, lane = tid & 63;
  for (int r = wv; r < 64; r += 8) {
    float v = cur[r][lane] * Wo[lane] + cur[r][64 + lane] * Wo[64 + lane];
    #pragma unroll
    for (int off = 32; off; off >>= 1) v += __shfl_down(v, off);
    if (lane == 0) out[r] = 1.0f / (1.0f + expf(-(v + bo[0])));
  }
}

// ---------------- launch ----------------

extern "C" void kernel_launch(void* const* d_in, const int* in_sizes, int n_in,
                              void* d_out, int out_size, void* d_ws, size_t ws_size,
                              hipStream_t stream) {
  const float* x1  = (const float*)d_in[0];
  const float* x2  = (const float*)d_in[1];
  const int* e1    = (const int*)d_in[2];
  const int* e2    = (const int*)d_in[3];
  const int* seg1  = (const int*)d_in[4];
  const int* seg2  = (const int*)d_in[5];
  const float* W1a = (const float*)d_in[6];  const float* b1a = (const float*)d_in[7];
  const float* g1a = (const float*)d_in[8];  const float* be1a = (const float*)d_in[9];
  const float* W1b = (const float*)d_in[10]; const float* b1b = (const float*)d_in[11];
  const float* g1b = (const float*)d_in[12]; const float* be1b = (const float*)d_in[13];
  const float* W2a = (const float*)d_in[14]; const float* b2a = (const float*)d_in[15];
  const float* g2a = (const float*)d_in[16]; const float* be2a = (const float*)d_in[17];
  const float* W2b = (const float*)d_in[18]; const float* b2b = (const float*)d_in[19];
  const float* g2b = (const float*)d_in[20]; const float* be2b = (const float*)d_in[21];
  const float* Wd  = (const float*)d_in[22]; const float* bd  = (const float*)d_in[23];
  const float* Wo  = (const float*)d_in[24]; const float* bo  = (const float*)d_in[25];
  float* out = (float*)d_out;

  const int N = in_sizes[0] / 128;
  const int E = in_sizes[2] / 2;

  char* ws = (char*)d_ws;
  size_t off = 0;
  auto alloc = [&](size_t bytes) -> void* {
    void* ptr = ws + off;
    off += (bytes + 255) & ~(size_t)255;
    return ptr;
  };
  float* h    = (float*)alloc((size_t)N * 128 * sizeof(float));
  float* aggb = (float*)alloc((size_t)N * 128 * sizeof(float));
  int* counts = (int*)alloc((size_t)N * sizeof(int));
  int* offs   = (int*)alloc((size_t)(N + 1) * sizeof(int));
  int* csr    = (int*)alloc((size_t)E * sizeof(int));
  float* pbuf = (float*)alloc(2 * 64 * 64 * sizeof(float));
  (void)ws_size; (void)n_in; (void)out_size;

  struct Branch {
    const float *x; const int *edges; const int *seg;
    const float *Wa, *ba, *ga, *bea, *Wb, *bb, *gb, *beb;
  };
  Branch brs[2] = {
    {x1, e1, seg1, W1a, b1a, g1a, be1a, W1b, b1b, g1b, be1b},
    {x2, e2, seg2, W2a, b2a, g2a, be2a, W2b, b2b, g2b, be2b},
  };

  for (int b = 0; b < 2; ++b) {
    const int* src = brs[b].edges;
    const int* dst = brs[b].edges + E;
    hipMemsetAsync(counts, 0, (size_t)N * sizeof(int), stream);
    hist_kernel<<<(E + 255) / 256, 256, 0, stream>>>(dst, counts, E);
    scan_kernel<<<1, 1024, 0, stream>>>(counts, offs, N);
    hipMemsetAsync(counts, 0, (size_t)N * sizeof(int), stream);
    fill_kernel<<<(E + 255) / 256, 256, 0, stream>>>(src, dst, offs, counts, csr, E);

    gemm_kernel<128><<<(N + 31) / 32, 256, 0, stream>>>(brs[b].x, brs[b].Wa, brs[b].ba, h, N);
    agg_kernel<128><<<(N + 3) / 4, 256, 0, stream>>>(h, offs, csr, brs[b].ga, brs[b].bea, aggb, N);
    gemm_kernel<64><<<(N + 63) / 64, 256, 0, stream>>>(aggb, brs[b].Wb, brs[b].bb, h, N);
    agg_kernel<64><<<(N + 3) / 4, 256, 0, stream>>>(h, offs, csr, brs[b].gb, brs[b].beb, aggb, N);
    pool_kernel<<<64, 256, 0, stream>>>(aggb, brs[b].seg, pbuf + b * 64 * 64, N);
  }
  head_kernel<<<1, 512, 0, stream>>>(pbuf, Wd, bd, Wo, bo, out);
}

// Round 2
// 898.859 us; speedup vs baseline: 2.8996x; 2.8996x over previous
//
#include <hip/hip_runtime.h>
#include <math.h>

// ---------------- CSR build ----------------

__global__ __launch_bounds__(256) void hist_kernel(const int* __restrict__ dst,
                                                   int* __restrict__ counts, int E) {
  int e = blockIdx.x * 256 + threadIdx.x;
  if (e < E) atomicAdd(&counts[dst[e]], 1);
}

__global__ __launch_bounds__(1024) void scan_kernel(const int* __restrict__ counts,
                                                    int* __restrict__ offs, int n) {
  __shared__ int sd[1024];
  __shared__ int carry_s;
  int tid = threadIdx.x;
  if (tid == 0) carry_s = 0;
  __syncthreads();
  for (int base = 0; base < n; base += 1024) {
    int i = base + tid;
    int v = (i < n) ? counts[i] : 0;
    sd[tid] = v;
    __syncthreads();
    #pragma unroll
    for (int off = 1; off < 1024; off <<= 1) {
      int t = (tid >= off) ? sd[tid - off] : 0;
      __syncthreads();
      sd[tid] += t;
      __syncthreads();
    }
    int incl = sd[tid];
    int carry = carry_s;
    __syncthreads();
    if (i < n) offs[i] = carry + incl - v;   // exclusive
    if (tid == 1023) carry_s = carry + incl;
    __syncthreads();
  }
  if (tid == 0) offs[n] = carry_s;
}

__global__ __launch_bounds__(256) void fill_kernel(const int* __restrict__ src,
                                                   const int* __restrict__ dst,
                                                   const int* __restrict__ offs,
                                                   int* __restrict__ cursor,
                                                   int* __restrict__ csr_src, int E) {
  int e = blockIdx.x * 256 + threadIdx.x;
  if (e < E) {
    int d = dst[e];
    int pos = atomicAdd(&cursor[d], 1);
    csr_src[offs[d] + pos] = src[e];
  }
}

// ---------------- GEMM: Y[nrows,COUT] = X[nrows,128] @ W[128,COUT] + bias ----------------
// Register-bounded: per-thread acc[RPT][4] (<=32 VGPR), k-loop unroll capped at 4,
// launch_bounds(256,2) caps VGPR at 128 -> no spill.

template <int COUT>
__global__ __launch_bounds__(256, 2) void gemm_kernel(const float* __restrict__ X,
                                                      const float* __restrict__ W,
                                                      const float* __restrict__ bias,
                                                      float* __restrict__ Y, int nrows) {
  constexpr int CG = COUT / 4;    // col groups of 4 cols: 32 (C=128) or 16 (C=64)
  constexpr int RG = 256 / CG;    // row groups: 8 or 16
  constexpr int BM = 64;          // rows per block
  constexpr int RPT = BM / RG;    // rows per thread: 8 or 4
  __shared__ float xs[BM][132];   // +4 pad
  int tid = threadIdx.x;
  int block_row = blockIdx.x * BM;
  for (int i = tid; i < BM * 32; i += 256) {
    int r = i >> 5, c4 = i & 31;
    int gr = block_row + r;
    float4 v = make_float4(0.f, 0.f, 0.f, 0.f);
    if (gr < nrows) v = reinterpret_cast<const float4*>(X + (size_t)gr * 128)[c4];
    *reinterpret_cast<float4*>(&xs[r][c4 * 4]) = v;
  }
  __syncthreads();
  int c0 = (tid % CG) * 4;
  int r0 = (tid / CG) * RPT;
  float acc[RPT][4] = {};
  #pragma unroll 4
  for (int k = 0; k < 128; ++k) {
    float4 w = *reinterpret_cast<const float4*>(&W[k * COUT + c0]);
    #pragma unroll
    for (int i = 0; i < RPT; ++i) {
      float x = xs[r0 + i][k];
      acc[i][0] = fmaf(x, w.x, acc[i][0]);
      acc[i][1] = fmaf(x, w.y, acc[i][1]);
      acc[i][2] = fmaf(x, w.z, acc[i][2]);
      acc[i][3] = fmaf(x, w.w, acc[i][3]);
    }
  }
  float4 bv = *reinterpret_cast<const float4*>(&bias[c0]);
  #pragma unroll
  for (int i = 0; i < RPT; ++i) {
    int gr = block_row + r0 + i;
    if (gr < nrows) {
      float4 o;
      o.x = acc[i][0] + bv.x; o.y = acc[i][1] + bv.y;
      o.z = acc[i][2] + bv.z; o.w = acc[i][3] + bv.w;
      *reinterpret_cast<float4*>(&Y[(size_t)gr * COUT + c0]) = o;
    }
  }
}

// ---------------- Aggregate (CSR gather-sum) + BN(inference) + relu ----------------

template <int C>
__global__ __launch_bounds__(256) void agg_kernel(const float* __restrict__ h,
                                                  const int* __restrict__ offs,
                                                  const int* __restrict__ csr_src,
                                                  const float* __restrict__ gamma,
                                                  const float* __restrict__ beta,
                                                  float* __restrict__ out, int n) {
  int node = blockIdx.x * 4 + (threadIdx.x >> 6);  // one wave per node
  if (node >= n) return;
  int lane = threadIdx.x & 63;
  int beg = offs[node], end = offs[node + 1];
  float a0 = 0.f, a1 = 0.f;
  for (int i = beg; i < end; ++i) {
    const float* row = h + (size_t)csr_src[i] * C;
    a0 += row[lane];
    if (C == 128) a1 += row[64 + lane];
  }
  const float inv = 1.0f / sqrtf(1.0f + 1.0e-3f);
  out[(size_t)node * C + lane] = fmaxf(fmaf(a0, gamma[lane] * inv, beta[lane]), 0.f);
  if (C == 128)
    out[(size_t)node * C + 64 + lane] =
        fmaxf(fmaf(a1, gamma[64 + lane] * inv, beta[64 + lane]), 0.f);
}

// ---------------- Segment mean pool (seg sorted): p[64,64] ----------------

__global__ __launch_bounds__(256) void pool_kernel(const float* __restrict__ h,
                                                   const int* __restrict__ seg,
                                                   float* __restrict__ p, int n) {
  int g = blockIdx.x;  // 0..63
  int lo, hi;
  { int l = 0, r = n; while (l < r) { int m = (l + r) >> 1; if (seg[m] < g) l = m + 1; else r = m; } lo = l; }
  { int l = 0, r = n; while (l < r) { int m = (l + r) >> 1; if (seg[m] < g + 1) l = m + 1; else r = m; } hi = l; }
  int c = threadIdx.x & 63;
  int sub = threadIdx.x >> 6;
  float acc = 0.f;
  for (int i = lo + sub; i < hi; i += 4) acc += h[(size_t)i * 64 + c];
  __shared__ float red[4][64];
  red[sub][c] = acc;
  __syncthreads();
  if (sub == 0) {
    float s = red[0][c] + red[1][c] + red[2][c] + red[3][c];
    float cnt = (float)(hi - lo);
    p[g * 64 + c] = s / fmaxf(cnt, 1.0f);
  }
}

// ---------------- Head: concat -> 2x Dense(128,relu, shared W) -> sigmoid ----------------

__global__ __launch_bounds__(512) void head_kernel(const float* __restrict__ p,
                                                   const float* __restrict__ Wd,
                                                   const float* __restrict__ bd,
                                                   const float* __restrict__ Wo,
                                                   const float* __restrict__ bo,
                                                   float* __restrict__ out) {
  __shared__ float cur[64][128];
  __shared__ float nxt[64][128];
  int tid = threadIdx.x;
  const float* p1 = p;
  const float* p2 = p + 64 * 64;
  for (int i = tid; i < 64 * 128; i += 512) {
    int r = i >> 7, c = i & 127;
    cur[r][c] = (c < 64) ? p1[r * 64 + c] : p2[r * 64 + (c - 64)];
  }
  __syncthreads();
  int c0 = (tid & 31) * 4;
  int r0 = (tid >> 5) * 4;
  for (int layer = 0; layer < 2; ++layer) {
    float acc[4][4] = {};
    #pragma unroll 4
    for (int k = 0; k < 128; ++k) {
      float4 w = *reinterpret_cast<const float4*>(&Wd[k * 128 + c0]);
      #pragma unroll
      for (int i = 0; i < 4; ++i) {
        float x = cur[r0 + i][k];
        acc[i][0] = fmaf(x, w.x, acc[i][0]);
        acc[i][1] = fmaf(x, w.y, acc[i][1]);
        acc[i][2] = fmaf(x, w.z, acc[i][2]);
        acc[i][3] = fmaf(x, w.w, acc[i][3]);
      }
    }
    float4 bv = *reinterpret_cast<const float4*>(&bd[c0]);
    __syncthreads();
    #pragma unroll
    for (int i = 0; i < 4; ++i) {
      float4 o;
      o.x = fmaxf(acc[i][0] + bv.x, 0.f);
      o.y = fmaxf(acc[i][1] + bv.y, 0.f);
      o.z = fmaxf(acc[i][2] + bv.z, 0.f);
      o.w = fmaxf(acc[i][3] + bv.w, 0.f);
      *reinterpret_cast<float4*>(&nxt[r0 + i][c0]) = o;
    }
    __syncthreads();
    for (int i = tid; i < 64 * 128; i += 512) (&cur[0][0])[i] = (&nxt[0][0])[i];
    __syncthreads();
  }
  int wv = tid >> 6, lane = tid & 63;
  for (int r = wv; r < 64; r += 8) {
    float v = cur[r][lane] * Wo[lane] + cur[r][64 + lane] * Wo[64 + lane];
    #pragma unroll
    for (int off = 32; off; off >>= 1) v += __shfl_down(v, off);
    if (lane == 0) out[r] = 1.0f / (1.0f + expf(-(v + bo[0])));
  }
}

// ---------------- launch ----------------

extern "C" void kernel_launch(void* const* d_in, const int* in_sizes, int n_in,
                              void* d_out, int out_size, void* d_ws, size_t ws_size,
                              hipStream_t stream) {
  const float* x1  = (const float*)d_in[0];
  const float* x2  = (const float*)d_in[1];
  const int* e1    = (const int*)d_in[2];
  const int* e2    = (const int*)d_in[3];
  const int* seg1  = (const int*)d_in[4];
  const int* seg2  = (const int*)d_in[5];
  const float* W1a = (const float*)d_in[6];  const float* b1a = (const float*)d_in[7];
  const float* g1a = (const float*)d_in[8];  const float* be1a = (const float*)d_in[9];
  const float* W1b = (const float*)d_in[10]; const float* b1b = (const float*)d_in[11];
  const float* g1b = (const float*)d_in[12]; const float* be1b = (const float*)d_in[13];
  const float* W2a = (const float*)d_in[14]; const float* b2a = (const float*)d_in[15];
  const float* g2a = (const float*)d_in[16]; const float* be2a = (const float*)d_in[17];
  const float* W2b = (const float*)d_in[18]; const float* b2b = (const float*)d_in[19];
  const float* g2b = (const float*)d_in[20]; const float* be2b = (const float*)d_in[21];
  const float* Wd  = (const float*)d_in[22]; const float* bd  = (const float*)d_in[23];
  const float* Wo  = (const float*)d_in[24]; const float* bo  = (const float*)d_in[25];
  float* out = (float*)d_out;

  const int N = in_sizes[0] / 128;
  const int E = in_sizes[2] / 2;

  char* ws = (char*)d_ws;
  size_t off = 0;
  auto alloc = [&](size_t bytes) -> void* {
    void* ptr = ws + off;
    off += (bytes + 255) & ~(size_t)255;
    return ptr;
  };
  float* h    = (float*)alloc((size_t)N * 128 * sizeof(float));
  float* aggb = (float*)alloc((size_t)N * 128 * sizeof(float));
  int* counts = (int*)alloc((size_t)N * sizeof(int));
  int* offs   = (int*)alloc((size_t)(N + 1) * sizeof(int));
  int* csr    = (int*)alloc((size_t)E * sizeof(int));
  float* pbuf = (float*)alloc(2 * 64 * 64 * sizeof(float));
  (void)ws_size; (void)n_in; (void)out_size;

  struct Branch {
    const float *x; const int *edges; const int *seg;
    const float *Wa, *ba, *ga, *bea, *Wb, *bb, *gb, *beb;
  };
  Branch brs[2] = {
    {x1, e1, seg1, W1a, b1a, g1a, be1a, W1b, b1b, g1b, be1b},
    {x2, e2, seg2, W2a, b2a, g2a, be2a, W2b, b2b, g2b, be2b},
  };

  for (int b = 0; b < 2; ++b) {
    const int* src = brs[b].edges;
    const int* dst = brs[b].edges + E;
    hipMemsetAsync(counts, 0, (size_t)N * sizeof(int), stream);
    hist_kernel<<<(E + 255) / 256, 256, 0, stream>>>(dst, counts, E);
    scan_kernel<<<1, 1024, 0, stream>>>(counts, offs, N);
    hipMemsetAsync(counts, 0, (size_t)N * sizeof(int), stream);
    fill_kernel<<<(E + 255) / 256, 256, 0, stream>>>(src, dst, offs, counts, csr, E);

    gemm_kernel<128><<<(N + 63) / 64, 256, 0, stream>>>(brs[b].x, brs[b].Wa, brs[b].ba, h, N);
    agg_kernel<128><<<(N + 3) / 4, 256, 0, stream>>>(h, offs, csr, brs[b].ga, brs[b].bea, aggb, N);
    gemm_kernel<64><<<(N + 63) / 64, 256, 0, stream>>>(aggb, brs[b].Wb, brs[b].bb, h, N);
    agg_kernel<64><<<(N + 3) / 4, 256, 0, stream>>>(h, offs, csr, brs[b].gb, brs[b].beb, aggb, N);
    pool_kernel<<<64, 256, 0, stream>>>(aggb, brs[b].seg, pbuf + b * 64 * 64, N);
  }
  head_kernel<<<1, 512, 0, stream>>>(pbuf, Wd, bd, Wo, bo, out);
}

// Round 3
// 600.004 us; speedup vs baseline: 4.3439x; 1.4981x over previous
//
#include <hip/hip_runtime.h>
#include <math.h>

// ---------------- CSR build ----------------

__global__ __launch_bounds__(256) void hist_kernel(const int* __restrict__ dst,
                                                   int* __restrict__ counts, int E) {
  int e = blockIdx.x * 256 + threadIdx.x;
  if (e < E) atomicAdd(&counts[dst[e]], 1);
}

// Per-wave shuffle scan + one atomicAdd per wave: assigns each node a contiguous
// CSR region (arbitrary global order -- only contiguity matters).
__global__ __launch_bounds__(256) void alloc_kernel(const int* __restrict__ counts,
                                                    int* __restrict__ offs,
                                                    int* __restrict__ gcur, int n) {
  int i = blockIdx.x * 256 + threadIdx.x;
  int lane = threadIdx.x & 63;
  int cnt = (i < n) ? counts[i] : 0;
  int v = cnt;
  #pragma unroll
  for (int off = 1; off < 64; off <<= 1) {
    int t = __shfl_up(v, off);
    if (lane >= off) v += t;
  }
  int base = 0;
  if (lane == 63) base = atomicAdd(gcur, v);
  base = __shfl(base, 63);
  if (i < n) offs[i] = base + v - cnt;
}

__global__ __launch_bounds__(256) void fill_kernel(const int* __restrict__ src,
                                                   const int* __restrict__ dst,
                                                   const int* __restrict__ offs,
                                                   int* __restrict__ cursor,
                                                   int* __restrict__ csr_src, int E) {
  int e = blockIdx.x * 256 + threadIdx.x;
  if (e < E) {
    int d = dst[e];
    int pos = atomicAdd(&cursor[d], 1);
    csr_src[offs[d] + pos] = src[e];
  }
}

// ---------------- GEMM: Y[nrows,COUT] = X[nrows,128] @ W[128,COUT] + bias ----------------

template <int COUT>
__global__ __launch_bounds__(256, 2) void gemm_kernel(const float* __restrict__ X,
                                                      const float* __restrict__ W,
                                                      const float* __restrict__ bias,
                                                      float* __restrict__ Y, int nrows) {
  constexpr int CG = COUT / 4;    // col groups of 4 cols
  constexpr int RG = 256 / CG;    // row groups
  constexpr int BM = 64;          // rows per block
  constexpr int RPT = BM / RG;    // rows per thread
  __shared__ float xs[BM][132];
  int tid = threadIdx.x;
  int block_row = blockIdx.x * BM;
  for (int i = tid; i < BM * 32; i += 256) {
    int r = i >> 5, c4 = i & 31;
    int gr = block_row + r;
    float4 v = make_float4(0.f, 0.f, 0.f, 0.f);
    if (gr < nrows) v = reinterpret_cast<const float4*>(X + (size_t)gr * 128)[c4];
    *reinterpret_cast<float4*>(&xs[r][c4 * 4]) = v;
  }
  __syncthreads();
  int c0 = (tid % CG) * 4;
  int r0 = (tid / CG) * RPT;
  float acc[RPT][4] = {};
  #pragma unroll 4
  for (int k = 0; k < 128; ++k) {
    float4 w = *reinterpret_cast<const float4*>(&W[k * COUT + c0]);
    #pragma unroll
    for (int i = 0; i < RPT; ++i) {
      float x = xs[r0 + i][k];
      acc[i][0] = fmaf(x, w.x, acc[i][0]);
      acc[i][1] = fmaf(x, w.y, acc[i][1]);
      acc[i][2] = fmaf(x, w.z, acc[i][2]);
      acc[i][3] = fmaf(x, w.w, acc[i][3]);
    }
  }
  float4 bv = *reinterpret_cast<const float4*>(&bias[c0]);
  #pragma unroll
  for (int i = 0; i < RPT; ++i) {
    int gr = block_row + r0 + i;
    if (gr < nrows) {
      float4 o;
      o.x = acc[i][0] + bv.x; o.y = acc[i][1] + bv.y;
      o.z = acc[i][2] + bv.z; o.w = acc[i][3] + bv.w;
      *reinterpret_cast<float4*>(&Y[(size_t)gr * COUT + c0]) = o;
    }
  }
}

// ---------------- Aggregate (CSR gather-sum) + BN(inference) + relu ----------------
// Wave per node. Indices loaded 64-at-a-time (one coalesced load), broadcast via
// shfl -> per-edge data loads are address-independent (deep MLP).

template <int C>
__global__ __launch_bounds__(256) void agg_kernel(const float* __restrict__ h,
                                                  const int* __restrict__ offs,
                                                  const int* __restrict__ counts,
                                                  const int* __restrict__ csr_src,
                                                  const float* __restrict__ gamma,
                                                  const float* __restrict__ beta,
                                                  float* __restrict__ out, int n) {
  int node = blockIdx.x * 4 + (threadIdx.x >> 6);
  if (node >= n) return;
  int lane = threadIdx.x & 63;
  int beg = offs[node], cnt = counts[node];
  float a0 = 0.f, a1 = 0.f;
  for (int base = 0; base < cnt; base += 64) {
    int m = min(64, cnt - base);
    int idx = (base + lane < cnt) ? csr_src[beg + base + lane] : 0;
    for (int j = 0; j < m; ++j) {
      int s = __shfl(idx, j);
      if (C == 128) {
        float2 v = *reinterpret_cast<const float2*>(h + (size_t)s * 128 + lane * 2);
        a0 += v.x; a1 += v.y;
      } else {
        a0 += h[(size_t)s * 64 + lane];
      }
    }
  }
  const float inv = 1.0f / sqrtf(1.0f + 1.0e-3f);
  if (C == 128) {
    float g0 = gamma[lane * 2] * inv, g1 = gamma[lane * 2 + 1] * inv;
    float b0 = beta[lane * 2], b1 = beta[lane * 2 + 1];
    float2 o;
    o.x = fmaxf(fmaf(a0, g0, b0), 0.f);
    o.y = fmaxf(fmaf(a1, g1, b1), 0.f);
    *reinterpret_cast<float2*>(out + (size_t)node * 128 + lane * 2) = o;
  } else {
    out[(size_t)node * 64 + lane] = fmaxf(fmaf(a0, gamma[lane] * inv, beta[lane]), 0.f);
  }
}

// ---------------- Segment mean pool (seg sorted): p[64,64] ----------------

__global__ __launch_bounds__(1024) void pool_kernel(const float* __restrict__ h,
                                                    const int* __restrict__ seg,
                                                    float* __restrict__ p, int n) {
  int g = blockIdx.x;  // 0..63
  int lo, hi;
  { int l = 0, r = n; while (l < r) { int m = (l + r) >> 1; if (seg[m] < g) l = m + 1; else r = m; } lo = l; }
  { int l = 0, r = n; while (l < r) { int m = (l + r) >> 1; if (seg[m] < g + 1) l = m + 1; else r = m; } hi = l; }
  int c = threadIdx.x & 63;
  int sub = threadIdx.x >> 6;  // 0..15
  float acc = 0.f;
  for (int i = lo + sub; i < hi; i += 16) acc += h[(size_t)i * 64 + c];
  __shared__ float red[16][64];
  red[sub][c] = acc;
  __syncthreads();
  if (sub == 0) {
    float s = 0.f;
    #pragma unroll
    for (int k = 0; k < 16; ++k) s += red[k][c];
    float cnt = (float)(hi - lo);
    p[g * 64 + c] = s / fmaxf(cnt, 1.0f);
  }
}

// ---------------- Head: concat -> 2x Dense(128,relu, shared W) -> sigmoid ----------------

__global__ __launch_bounds__(512) void head_kernel(const float* __restrict__ p,
                                                   const float* __restrict__ Wd,
                                                   const float* __restrict__ bd,
                                                   const float* __restrict__ Wo,
                                                   const float* __restrict__ bo,
                                                   float* __restrict__ out) {
  __shared__ float cur[64][128];
  __shared__ float nxt[64][128];
  int tid = threadIdx.x;
  const float* p1 = p;
  const float* p2 = p + 64 * 64;
  for (int i = tid; i < 64 * 128; i += 512) {
    int r = i >> 7, c = i & 127;
    cur[r][c] = (c < 64) ? p1[r * 64 + c] : p2[r * 64 + (c - 64)];
  }
  __syncthreads();
  int c0 = (tid & 31) * 4;
  int r0 = (tid >> 5) * 4;
  for (int layer = 0; layer < 2; ++layer) {
    float acc[4][4] = {};
    #pragma unroll 4
    for (int k = 0; k < 128; ++k) {
      float4 w = *reinterpret_cast<const float4*>(&Wd[k * 128 + c0]);
      #pragma unroll
      for (int i = 0; i < 4; ++i) {
        float x = cur[r0 + i][k];
        acc[i][0] = fmaf(x, w.x, acc[i][0]);
        acc[i][1] = fmaf(x, w.y, acc[i][1]);
        acc[i][2] = fmaf(x, w.z, acc[i][2]);
        acc[i][3] = fmaf(x, w.w, acc[i][3]);
      }
    }
    float4 bv = *reinterpret_cast<const float4*>(&bd[c0]);
    __syncthreads();
    #pragma unroll
    for (int i = 0; i < 4; ++i) {
      float4 o;
      o.x = fmaxf(acc[i][0] + bv.x, 0.f);
      o.y = fmaxf(acc[i][1] + bv.y, 0.f);
      o.z = fmaxf(acc[i][2] + bv.z, 0.f);
      o.w = fmaxf(acc[i][3] + bv.w, 0.f);
      *reinterpret_cast<float4*>(&nxt[r0 + i][c0]) = o;
    }
    __syncthreads();
    for (int i = tid; i < 64 * 128; i += 512) (&cur[0][0])[i] = (&nxt[0][0])[i];
    __syncthreads();
  }
  int wv = tid >> 6, lane = tid & 63;
  for (int r = wv; r < 64; r += 8) {
    float v = cur[r][lane] * Wo[lane] + cur[r][64 + lane] * Wo[64 + lane];
    #pragma unroll
    for (int off = 32; off; off >>= 1) v += __shfl_down(v, off);
    if (lane == 0) out[r] = 1.0f / (1.0f + expf(-(v + bo[0])));
  }
}

// ---------------- launch ----------------

extern "C" void kernel_launch(void* const* d_in, const int* in_sizes, int n_in,
                              void* d_out, int out_size, void* d_ws, size_t ws_size,
                              hipStream_t stream) {
  const float* x1  = (const float*)d_in[0];
  const float* x2  = (const float*)d_in[1];
  const int* e1    = (const int*)d_in[2];
  const int* e2    = (const int*)d_in[3];
  const int* seg1  = (const int*)d_in[4];
  const int* seg2  = (const int*)d_in[5];
  const float* W1a = (const float*)d_in[6];  const float* b1a = (const float*)d_in[7];
  const float* g1a = (const float*)d_in[8];  const float* be1a = (const float*)d_in[9];
  const float* W1b = (const float*)d_in[10]; const float* b1b = (const float*)d_in[11];
  const float* g1b = (const float*)d_in[12]; const float* be1b = (const float*)d_in[13];
  const float* W2a = (const float*)d_in[14]; const float* b2a = (const float*)d_in[15];
  const float* g2a = (const float*)d_in[16]; const float* be2a = (const float*)d_in[17];
  const float* W2b = (const float*)d_in[18]; const float* b2b = (const float*)d_in[19];
  const float* g2b = (const float*)d_in[20]; const float* be2b = (const float*)d_in[21];
  const float* Wd  = (const float*)d_in[22]; const float* bd  = (const float*)d_in[23];
  const float* Wo  = (const float*)d_in[24]; const float* bo  = (const float*)d_in[25];
  float* out = (float*)d_out;

  const int N = in_sizes[0] / 128;
  const int E = in_sizes[2] / 2;

  char* ws = (char*)d_ws;
  size_t off = 0;
  auto alloc = [&](size_t bytes) -> void* {
    void* ptr = ws + off;
    off += (bytes + 255) & ~(size_t)255;
    return ptr;
  };
  float* h    = (float*)alloc((size_t)N * 128 * sizeof(float));
  float* aggb = (float*)alloc((size_t)N * 128 * sizeof(float));
  // contiguous int scratch: [counts N][cursor2 N][gcur 1] -> one memset
  int* counts = (int*)alloc((size_t)(2 * N + 1) * sizeof(int));
  int* cursor2 = counts + N;
  int* gcur    = counts + 2 * N;
  int* offs   = (int*)alloc((size_t)N * sizeof(int));
  int* csr    = (int*)alloc((size_t)E * sizeof(int));
  float* pbuf = (float*)alloc(2 * 64 * 64 * sizeof(float));
  (void)ws_size; (void)n_in; (void)out_size;

  struct Branch {
    const float *x; const int *edges; const int *seg;
    const float *Wa, *ba, *ga, *bea, *Wb, *bb, *gb, *beb;
  };
  Branch brs[2] = {
    {x1, e1, seg1, W1a, b1a, g1a, be1a, W1b, b1b, g1b, be1b},
    {x2, e2, seg2, W2a, b2a, g2a, be2a, W2b, b2b, g2b, be2b},
  };

  for (int b = 0; b < 2; ++b) {
    const int* src = brs[b].edges;
    const int* dst = brs[b].edges + E;
    hipMemsetAsync(counts, 0, (size_t)(2 * N + 1) * sizeof(int), stream);
    hist_kernel<<<(E + 255) / 256, 256, 0, stream>>>(dst, counts, E);
    alloc_kernel<<<(N + 255) / 256, 256, 0, stream>>>(counts, offs, gcur, N);
    fill_kernel<<<(E + 255) / 256, 256, 0, stream>>>(src, dst, offs, cursor2, csr, E);

    gemm_kernel<128><<<(N + 63) / 64, 256, 0, stream>>>(brs[b].x, brs[b].Wa, brs[b].ba, h, N);
    agg_kernel<128><<<(N + 3) / 4, 256, 0, stream>>>(h, offs, counts, csr, brs[b].ga, brs[b].bea, aggb, N);
    gemm_kernel<64><<<(N + 63) / 64, 256, 0, stream>>>(aggb, brs[b].Wb, brs[b].bb, h, N);
    agg_kernel<64><<<(N + 3) / 4, 256, 0, stream>>>(h, offs, counts, csr, brs[b].gb, brs[b].beb, aggb, N);
    pool_kernel<<<64, 1024, 0, stream>>>(aggb, brs[b].seg, pbuf + b * 64 * 64, N);
  }
  head_kernel<<<1, 512, 0, stream>>>(pbuf, Wd, bd, Wo, bo, out);
}

// Round 4
// 541.115 us; speedup vs baseline: 4.8167x; 1.1088x over previous
//
#include <hip/hip_runtime.h>
#include <math.h>

// ---------------- CSR build ----------------

__global__ __launch_bounds__(256) void hist_kernel(const int* __restrict__ dst,
                                                   int* __restrict__ counts, int E) {
  int e = blockIdx.x * 256 + threadIdx.x;
  if (e < E) atomicAdd(&counts[dst[e]], 1);
}

// Per-wave shuffle scan + one atomicAdd per wave: assigns each node a contiguous
// CSR region (arbitrary global order -- only contiguity matters).
__global__ __launch_bounds__(256) void alloc_kernel(const int* __restrict__ counts,
                                                    int* __restrict__ offs,
                                                    int* __restrict__ gcur, int n) {
  int i = blockIdx.x * 256 + threadIdx.x;
  int lane = threadIdx.x & 63;
  int cnt = (i < n) ? counts[i] : 0;
  int v = cnt;
  #pragma unroll
  for (int off = 1; off < 64; off <<= 1) {
    int t = __shfl_up(v, off);
    if (lane >= off) v += t;
  }
  int base = 0;
  if (lane == 63) base = atomicAdd(gcur, v);
  base = __shfl(base, 63);
  if (i < n) offs[i] = base + v - cnt;
}

__global__ __launch_bounds__(256) void fill_kernel(const int* __restrict__ src,
                                                   const int* __restrict__ dst,
                                                   const int* __restrict__ offs,
                                                   int* __restrict__ cursor,
                                                   int* __restrict__ csr_src, int E) {
  int e = blockIdx.x * 256 + threadIdx.x;
  if (e < E) {
    int d = dst[e];
    int pos = atomicAdd(&cursor[d], 1);
    csr_src[offs[d] + pos] = src[e];
  }
}

// ---------------- GEMM: Y[nrows,COUT] = X[nrows,128] @ W[128,COUT] + bias ----------------

template <int COUT>
__global__ __launch_bounds__(256, 2) void gemm_kernel(const float* __restrict__ X,
                                                      const float* __restrict__ W,
                                                      const float* __restrict__ bias,
                                                      float* __restrict__ Y, int nrows) {
  constexpr int CG = COUT / 4;    // col groups of 4 cols
  constexpr int RG = 256 / CG;    // row groups
  constexpr int BM = 64;          // rows per block
  constexpr int RPT = BM / RG;    // rows per thread
  __shared__ float xs[BM][132];
  int tid = threadIdx.x;
  int block_row = blockIdx.x * BM;
  for (int i = tid; i < BM * 32; i += 256) {
    int r = i >> 5, c4 = i & 31;
    int gr = block_row + r;
    float4 v = make_float4(0.f, 0.f, 0.f, 0.f);
    if (gr < nrows) v = reinterpret_cast<const float4*>(X + (size_t)gr * 128)[c4];
    *reinterpret_cast<float4*>(&xs[r][c4 * 4]) = v;
  }
  __syncthreads();
  int c0 = (tid % CG) * 4;
  int r0 = (tid / CG) * RPT;
  float acc[RPT][4] = {};
  #pragma unroll 4
  for (int k = 0; k < 128; ++k) {
    float4 w = *reinterpret_cast<const float4*>(&W[k * COUT + c0]);
    #pragma unroll
    for (int i = 0; i < RPT; ++i) {
      float x = xs[r0 + i][k];
      acc[i][0] = fmaf(x, w.x, acc[i][0]);
      acc[i][1] = fmaf(x, w.y, acc[i][1]);
      acc[i][2] = fmaf(x, w.z, acc[i][2]);
      acc[i][3] = fmaf(x, w.w, acc[i][3]);
    }
  }
  float4 bv = *reinterpret_cast<const float4*>(&bias[c0]);
  #pragma unroll
  for (int i = 0; i < RPT; ++i) {
    int gr = block_row + r0 + i;
    if (gr < nrows) {
      float4 o;
      o.x = acc[i][0] + bv.x; o.y = acc[i][1] + bv.y;
      o.z = acc[i][2] + bv.z; o.w = acc[i][3] + bv.w;
      *reinterpret_cast<float4*>(&Y[(size_t)gr * COUT + c0]) = o;
    }
  }
}

// ---------------- Aggregate (CSR gather-sum) + BN(inference) + relu ----------------
// Wave per node. Indices preloaded coalesced + shfl-broadcast. Inner loop unrolled
// x8 with 8 independent in-flight loads -> one vmcnt wait per 8 edges (latency /8).

template <int C>
__global__ __launch_bounds__(256) void agg_kernel(const float* __restrict__ h,
                                                  const int* __restrict__ offs,
                                                  const int* __restrict__ counts,
                                                  const int* __restrict__ csr_src,
                                                  const float* __restrict__ gamma,
                                                  const float* __restrict__ beta,
                                                  float* __restrict__ out, int n) {
  int node = blockIdx.x * 4 + (threadIdx.x >> 6);
  if (node >= n) return;
  int lane = threadIdx.x & 63;
  int beg = offs[node], cnt = counts[node];
  float a0 = 0.f, a1 = 0.f;
  for (int base = 0; base < cnt; base += 64) {
    int m = min(64, cnt - base);
    int idx = (base + lane < cnt) ? csr_src[beg + base + lane] : 0;
    for (int j = 0; j < m; j += 8) {
      if (C == 128) {
        float2 v[8];
        #pragma unroll
        for (int u = 0; u < 8; ++u) {
          int s = __shfl(idx, min(j + u, m - 1));   // clamp: dup loads past end, masked below
          v[u] = *reinterpret_cast<const float2*>(h + (size_t)s * 128 + lane * 2);
        }
        #pragma unroll
        for (int u = 0; u < 8; ++u) {
          bool ok = (j + u) < m;
          a0 += ok ? v[u].x : 0.f;
          a1 += ok ? v[u].y : 0.f;
        }
      } else {
        float v[8];
        #pragma unroll
        for (int u = 0; u < 8; ++u) {
          int s = __shfl(idx, min(j + u, m - 1));
          v[u] = h[(size_t)s * 64 + lane];
        }
        #pragma unroll
        for (int u = 0; u < 8; ++u) {
          bool ok = (j + u) < m;
          a0 += ok ? v[u] : 0.f;
        }
      }
    }
  }
  const float inv = 1.0f / sqrtf(1.0f + 1.0e-3f);
  if (C == 128) {
    float g0 = gamma[lane * 2] * inv, g1 = gamma[lane * 2 + 1] * inv;
    float b0 = beta[lane * 2], b1 = beta[lane * 2 + 1];
    float2 o;
    o.x = fmaxf(fmaf(a0, g0, b0), 0.f);
    o.y = fmaxf(fmaf(a1, g1, b1), 0.f);
    *reinterpret_cast<float2*>(out + (size_t)node * 128 + lane * 2) = o;
  } else {
    out[(size_t)node * 64 + lane] = fmaxf(fmaf(a0, gamma[lane] * inv, beta[lane]), 0.f);
  }
}

// ---------------- Segment mean pool (seg sorted): p[64,64] ----------------

__global__ __launch_bounds__(1024) void pool_kernel(const float* __restrict__ h,
                                                    const int* __restrict__ seg,
                                                    float* __restrict__ p, int n) {
  int g = blockIdx.x;  // 0..63
  int lo, hi;
  { int l = 0, r = n; while (l < r) { int m = (l + r) >> 1; if (seg[m] < g) l = m + 1; else r = m; } lo = l; }
  { int l = 0, r = n; while (l < r) { int m = (l + r) >> 1; if (seg[m] < g + 1) l = m + 1; else r = m; } hi = l; }
  int c = threadIdx.x & 63;
  int sub = threadIdx.x >> 6;  // 0..15
  float acc = 0.f;
  for (int i = lo + sub; i < hi; i += 16) acc += h[(size_t)i * 64 + c];
  __shared__ float red[16][64];
  red[sub][c] = acc;
  __syncthreads();
  if (sub == 0) {
    float s = 0.f;
    #pragma unroll
    for (int k = 0; k < 16; ++k) s += red[k][c];
    float cnt = (float)(hi - lo);
    p[g * 64 + c] = s / fmaxf(cnt, 1.0f);
  }
}

// ---------------- Head: concat -> 2x Dense(128,relu, shared W) -> sigmoid ----------------

__global__ __launch_bounds__(512) void head_kernel(const float* __restrict__ p,
                                                   const float* __restrict__ Wd,
                                                   const float* __restrict__ bd,
                                                   const float* __restrict__ Wo,
                                                   const float* __restrict__ bo,
                                                   float* __restrict__ out) {
  __shared__ float cur[64][128];
  __shared__ float nxt[64][128];
  int tid = threadIdx.x;
  const float* p1 = p;
  const float* p2 = p + 64 * 64;
  for (int i = tid; i < 64 * 128; i += 512) {
    int r = i >> 7, c = i & 127;
    cur[r][c] = (c < 64) ? p1[r * 64 + c] : p2[r * 64 + (c - 64)];
  }
  __syncthreads();
  int c0 = (tid & 31) * 4;
  int r0 = (tid >> 5) * 4;
  for (int layer = 0; layer < 2; ++layer) {
    float acc[4][4] = {};
    #pragma unroll 4
    for (int k = 0; k < 128; ++k) {
      float4 w = *reinterpret_cast<const float4*>(&Wd[k * 128 + c0]);
      #pragma unroll
      for (int i = 0; i < 4; ++i) {
        float x = cur[r0 + i][k];
        acc[i][0] = fmaf(x, w.x, acc[i][0]);
        acc[i][1] = fmaf(x, w.y, acc[i][1]);
        acc[i][2] = fmaf(x, w.z, acc[i][2]);
        acc[i][3] = fmaf(x, w.w, acc[i][3]);
      }
    }
    float4 bv = *reinterpret_cast<const float4*>(&bd[c0]);
    __syncthreads();
    #pragma unroll
    for (int i = 0; i < 4; ++i) {
      float4 o;
      o.x = fmaxf(acc[i][0] + bv.x, 0.f);
      o.y = fmaxf(acc[i][1] + bv.y, 0.f);
      o.z = fmaxf(acc[i][2] + bv.z, 0.f);
      o.w = fmaxf(acc[i][3] + bv.w, 0.f);
      *reinterpret_cast<float4*>(&nxt[r0 + i][c0]) = o;
    }
    __syncthreads();
    for (int i = tid; i < 64 * 128; i += 512) (&cur[0][0])[i] = (&nxt[0][0])[i];
    __syncthreads();
  }
  int wv = tid >> 6, lane = tid & 63;
  for (int r = wv; r < 64; r += 8) {
    float v = cur[r][lane] * Wo[lane] + cur[r][64 + lane] * Wo[64 + lane];
    #pragma unroll
    for (int off = 32; off; off >>= 1) v += __shfl_down(v, off);
    if (lane == 0) out[r] = 1.0f / (1.0f + expf(-(v + bo[0])));
  }
}

// ---------------- launch ----------------

extern "C" void kernel_launch(void* const* d_in, const int* in_sizes, int n_in,
                              void* d_out, int out_size, void* d_ws, size_t ws_size,
                              hipStream_t stream) {
  const float* x1  = (const float*)d_in[0];
  const float* x2  = (const float*)d_in[1];
  const int* e1    = (const int*)d_in[2];
  const int* e2    = (const int*)d_in[3];
  const int* seg1  = (const int*)d_in[4];
  const int* seg2  = (const int*)d_in[5];
  const float* W1a = (const float*)d_in[6];  const float* b1a = (const float*)d_in[7];
  const float* g1a = (const float*)d_in[8];  const float* be1a = (const float*)d_in[9];
  const float* W1b = (const float*)d_in[10]; const float* b1b = (const float*)d_in[11];
  const float* g1b = (const float*)d_in[12]; const float* be1b = (const float*)d_in[13];
  const float* W2a = (const float*)d_in[14]; const float* b2a = (const float*)d_in[15];
  const float* g2a = (const float*)d_in[16]; const float* be2a = (const float*)d_in[17];
  const float* W2b = (const float*)d_in[18]; const float* b2b = (const float*)d_in[19];
  const float* g2b = (const float*)d_in[20]; const float* be2b = (const float*)d_in[21];
  const float* Wd  = (const float*)d_in[22]; const float* bd  = (const float*)d_in[23];
  const float* Wo  = (const float*)d_in[24]; const float* bo  = (const float*)d_in[25];
  float* out = (float*)d_out;

  const int N = in_sizes[0] / 128;
  const int E = in_sizes[2] / 2;

  char* ws = (char*)d_ws;
  size_t off = 0;
  auto alloc = [&](size_t bytes) -> void* {
    void* ptr = ws + off;
    off += (bytes + 255) & ~(size_t)255;
    return ptr;
  };
  float* h    = (float*)alloc((size_t)N * 128 * sizeof(float));
  float* aggb = (float*)alloc((size_t)N * 128 * sizeof(float));
  // contiguous int scratch: [counts N][cursor2 N][gcur 1] -> one memset
  int* counts = (int*)alloc((size_t)(2 * N + 1) * sizeof(int));
  int* cursor2 = counts + N;
  int* gcur    = counts + 2 * N;
  int* offs   = (int*)alloc((size_t)N * sizeof(int));
  int* csr    = (int*)alloc((size_t)E * sizeof(int));
  float* pbuf = (float*)alloc(2 * 64 * 64 * sizeof(float));
  (void)ws_size; (void)n_in; (void)out_size;

  struct Branch {
    const float *x; const int *edges; const int *seg;
    const float *Wa, *ba, *ga, *bea, *Wb, *bb, *gb, *beb;
  };
  Branch brs[2] = {
    {x1, e1, seg1, W1a, b1a, g1a, be1a, W1b, b1b, g1b, be1b},
    {x2, e2, seg2, W2a, b2a, g2a, be2a, W2b, b2b, g2b, be2b},
  };

  for (int b = 0; b < 2; ++b) {
    const int* src = brs[b].edges;
    const int* dst = brs[b].edges + E;
    hipMemsetAsync(counts, 0, (size_t)(2 * N + 1) * sizeof(int), stream);
    hist_kernel<<<(E + 255) / 256, 256, 0, stream>>>(dst, counts, E);
    alloc_kernel<<<(N + 255) / 256, 256, 0, stream>>>(counts, offs, gcur, N);
    fill_kernel<<<(E + 255) / 256, 256, 0, stream>>>(src, dst, offs, cursor2, csr, E);

    gemm_kernel<128><<<(N + 63) / 64, 256, 0, stream>>>(brs[b].x, brs[b].Wa, brs[b].ba, h, N);
    agg_kernel<128><<<(N + 3) / 4, 256, 0, stream>>>(h, offs, counts, csr, brs[b].ga, brs[b].bea, aggb, N);
    gemm_kernel<64><<<(N + 63) / 64, 256, 0, stream>>>(aggb, brs[b].Wb, brs[b].bb, h, N);
    agg_kernel<64><<<(N + 3) / 4, 256, 0, stream>>>(h, offs, counts, csr, brs[b].gb, brs[b].beb, aggb, N);
    pool_kernel<<<64, 1024, 0, stream>>>(aggb, brs[b].seg, pbuf + b * 64 * 64, N);
  }
  head_kernel<<<1, 512, 0, stream>>>(pbuf, Wd, bd, Wo, bo, out);
}

// Round 5
// 514.140 us; speedup vs baseline: 5.0694x; 1.0525x over previous
//
#include <hip/hip_runtime.h>
#include <math.h>

// ---------------- CSR build (both branches fused; single cursor over 2E) ----------------

__global__ __launch_bounds__(256) void hist2_kernel(const int* __restrict__ d1,
                                                    const int* __restrict__ d2,
                                                    int* __restrict__ counts, int E, int N) {
  int e = blockIdx.x * 256 + threadIdx.x;
  const int* dst = blockIdx.y ? d2 : d1;
  int nb = blockIdx.y * N;
  if (e < E) atomicAdd(&counts[nb + dst[e]], 1);
}

// Per-wave shuffle scan + one atomicAdd per wave over 2N nodes -> contiguous CSR regions.
__global__ __launch_bounds__(256) void alloc_kernel(const int* __restrict__ counts,
                                                    int* __restrict__ offs,
                                                    int* __restrict__ gcur, int n2) {
  int i = blockIdx.x * 256 + threadIdx.x;
  int lane = threadIdx.x & 63;
  int cnt = (i < n2) ? counts[i] : 0;
  int v = cnt;
  #pragma unroll
  for (int off = 1; off < 64; off <<= 1) {
    int t = __shfl_up(v, off);
    if (lane >= off) v += t;
  }
  int base = 0;
  if (lane == 63) base = atomicAdd(gcur, v);
  base = __shfl(base, 63);
  if (i < n2) offs[i] = base + v - cnt;
}

__global__ __launch_bounds__(256) void fill2_kernel(const int* __restrict__ s1,
                                                    const int* __restrict__ d1,
                                                    const int* __restrict__ s2,
                                                    const int* __restrict__ d2,
                                                    const int* __restrict__ offs,
                                                    int* __restrict__ cursor,
                                                    int* __restrict__ csr, int E, int N) {
  int e = blockIdx.x * 256 + threadIdx.x;
  const int* src = blockIdx.y ? s2 : s1;
  const int* dst = blockIdx.y ? d2 : d1;
  int nb = blockIdx.y * N;
  if (e < E) {
    int d = nb + dst[e];
    int pos = atomicAdd(&cursor[d], 1);
    csr[offs[d] + pos] = src[e];
  }
}

// ---------------- GEMM: Y[nrows,COUT] = X[nrows,128] @ W[128,COUT] + bias ----------------
// ds_read_b128 X fragments (broadcast within half-wave, conflict-free), k-step 4.

template <int COUT>
__global__ __launch_bounds__(256, 2) void gemm_kernel(const float* __restrict__ X,
                                                      const float* __restrict__ W,
                                                      const float* __restrict__ bias,
                                                      float* __restrict__ Y, int nrows) {
  constexpr int CG = COUT / 4;    // col groups of 4 cols: 32 / 16
  constexpr int RG = 256 / CG;    // row groups: 8 / 16
  constexpr int BM = 64;          // rows per block
  constexpr int RPT = BM / RG;    // rows per thread: 8 / 4
  __shared__ float xs[BM][132];
  int tid = threadIdx.x;
  int block_row = blockIdx.x * BM;
  for (int i = tid; i < BM * 32; i += 256) {
    int r = i >> 5, c4 = i & 31;
    int gr = block_row + r;
    float4 v = make_float4(0.f, 0.f, 0.f, 0.f);
    if (gr < nrows) v = reinterpret_cast<const float4*>(X + (size_t)gr * 128)[c4];
    *reinterpret_cast<float4*>(&xs[r][c4 * 4]) = v;
  }
  __syncthreads();
  int c0 = (tid % CG) * 4;
  int r0 = (tid / CG) * RPT;
  float acc[RPT][4] = {};
  #pragma unroll 2
  for (int k = 0; k < 128; k += 4) {
    float4 w0 = *reinterpret_cast<const float4*>(&W[(k + 0) * COUT + c0]);
    float4 w1 = *reinterpret_cast<const float4*>(&W[(k + 1) * COUT + c0]);
    float4 w2 = *reinterpret_cast<const float4*>(&W[(k + 2) * COUT + c0]);
    float4 w3 = *reinterpret_cast<const float4*>(&W[(k + 3) * COUT + c0]);
    #pragma unroll
    for (int i = 0; i < RPT; ++i) {
      float4 x = *reinterpret_cast<const float4*>(&xs[r0 + i][k]);
      acc[i][0] = fmaf(x.x, w0.x, acc[i][0]);
      acc[i][1] = fmaf(x.x, w0.y, acc[i][1]);
      acc[i][2] = fmaf(x.x, w0.z, acc[i][2]);
      acc[i][3] = fmaf(x.x, w0.w, acc[i][3]);
      acc[i][0] = fmaf(x.y, w1.x, acc[i][0]);
      acc[i][1] = fmaf(x.y, w1.y, acc[i][1]);
      acc[i][2] = fmaf(x.y, w1.z, acc[i][2]);
      acc[i][3] = fmaf(x.y, w1.w, acc[i][3]);
      acc[i][0] = fmaf(x.z, w2.x, acc[i][0]);
      acc[i][1] = fmaf(x.z, w2.y, acc[i][1]);
      acc[i][2] = fmaf(x.z, w2.z, acc[i][2]);
      acc[i][3] = fmaf(x.z, w2.w, acc[i][3]);
      acc[i][0] = fmaf(x.w, w3.x, acc[i][0]);
      acc[i][1] = fmaf(x.w, w3.y, acc[i][1]);
      acc[i][2] = fmaf(x.w, w3.z, acc[i][2]);
      acc[i][3] = fmaf(x.w, w3.w, acc[i][3]);
    }
  }
  float4 bv = *reinterpret_cast<const float4*>(&bias[c0]);
  #pragma unroll
  for (int i = 0; i < RPT; ++i) {
    int gr = block_row + r0 + i;
    if (gr < nrows) {
      float4 o;
      o.x = acc[i][0] + bv.x; o.y = acc[i][1] + bv.y;
      o.z = acc[i][2] + bv.z; o.w = acc[i][3] + bv.w;
      *reinterpret_cast<float4*>(&Y[(size_t)gr * COUT + c0]) = o;
    }
  }
}

// ---------------- Aggregate (CSR gather-sum) + BN(inference) + relu ----------------
// Wave per node (node forced wave-uniform -> scalar offs/counts loads). Indices loaded
// coalesced, broadcast via v_readlane (SGPR result) -> saddr-form loads with a single
// loop-invariant lane offset; address math on SALU. Clean 8-chunks; one masked tail.

template <int C>
__global__ __launch_bounds__(256) void agg_kernel(const float* __restrict__ h,
                                                  const int* __restrict__ offs,
                                                  const int* __restrict__ counts,
                                                  const int* __restrict__ csr_src,
                                                  const float* __restrict__ gamma,
                                                  const float* __restrict__ beta,
                                                  float* __restrict__ out, int n) {
  int node = blockIdx.x * 4 + (threadIdx.x >> 6);
  if (node >= n) return;
  node = __builtin_amdgcn_readfirstlane(node);
  int lane = threadIdx.x & 63;
  int beg = offs[node], cnt = counts[node];
  const int* lp = csr_src + beg;
  float a0 = 0.f, a1 = 0.f;
  for (int base = 0; base < cnt; base += 64) {
    int rem = cnt - base;
    int m = rem < 64 ? rem : 64;
    int idx = lp[base + (lane < m ? lane : 0)];
    int mfull = m & ~7;
    int j = 0;
    for (; j < mfull; j += 8) {
      if (C == 128) {
        float2 v[8];
        #pragma unroll
        for (int u = 0; u < 8; ++u) {
          int s = __builtin_amdgcn_readlane(idx, j + u);
          v[u] = *reinterpret_cast<const float2*>(h + (size_t)s * 128 + lane * 2);
        }
        #pragma unroll
        for (int u = 0; u < 8; ++u) { a0 += v[u].x; a1 += v[u].y; }
      } else {
        float v[8];
        #pragma unroll
        for (int u = 0; u < 8; ++u) {
          int s = __builtin_amdgcn_readlane(idx, j + u);
          v[u] = h[(size_t)s * 64 + lane];
        }
        #pragma unroll
        for (int u = 0; u < 8; ++u) a0 += v[u];
      }
    }
    if (j < m) {  // masked tail chunk (<=7 live edges)
      if (C == 128) {
        float2 v[8];
        #pragma unroll
        for (int u = 0; u < 8; ++u) {
          int jj = (j + u < m) ? (j + u) : (m - 1);
          int s = __builtin_amdgcn_readlane(idx, jj);
          v[u] = *reinterpret_cast<const float2*>(h + (size_t)s * 128 + lane * 2);
        }
        #pragma unroll
        for (int u = 0; u < 8; ++u) {
          bool ok = (j + u) < m;
          a0 += ok ? v[u].x : 0.f;
          a1 += ok ? v[u].y : 0.f;
        }
      } else {
        float v[8];
        #pragma unroll
        for (int u = 0; u < 8; ++u) {
          int jj = (j + u < m) ? (j + u) : (m - 1);
          int s = __builtin_amdgcn_readlane(idx, jj);
          v[u] = h[(size_t)s * 64 + lane];
        }
        #pragma unroll
        for (int u = 0; u < 8; ++u) a0 += ((j + u) < m) ? v[u] : 0.f;
      }
    }
  }
  const float inv = 1.0f / sqrtf(1.0f + 1.0e-3f);
  if (C == 128) {
    float g0 = gamma[lane * 2] * inv, g1 = gamma[lane * 2 + 1] * inv;
    float b0 = beta[lane * 2], b1 = beta[lane * 2 + 1];
    float2 o;
    o.x = fmaxf(fmaf(a0, g0, b0), 0.f);
    o.y = fmaxf(fmaf(a1, g1, b1), 0.f);
    *reinterpret_cast<float2*>(out + (size_t)node * 128 + lane * 2) = o;
  } else {
    out[(size_t)node * 64 + lane] = fmaxf(fmaf(a0, gamma[lane] * inv, beta[lane]), 0.f);
  }
}

// ---------------- Segment mean pool (seg sorted): p[64,64] ----------------

__global__ __launch_bounds__(1024) void pool_kernel(const float* __restrict__ h,
                                                    const int* __restrict__ seg,
                                                    float* __restrict__ p, int n) {
  int g = blockIdx.x;  // 0..63
  int lo, hi;
  { int l = 0, r = n; while (l < r) { int m = (l + r) >> 1; if (seg[m] < g) l = m + 1; else r = m; } lo = l; }
  { int l = 0, r = n; while (l < r) { int m = (l + r) >> 1; if (seg[m] < g + 1) l = m + 1; else r = m; } hi = l; }
  int c = threadIdx.x & 63;
  int sub = threadIdx.x >> 6;  // 0..15
  float acc = 0.f;
  for (int i = lo + sub; i < hi; i += 16) acc += h[(size_t)i * 64 + c];
  __shared__ float red[16][64];
  red[sub][c] = acc;
  __syncthreads();
  if (sub == 0) {
    float s = 0.f;
    #pragma unroll
    for (int k = 0; k < 16; ++k) s += red[k][c];
    float cnt = (float)(hi - lo);
    p[g * 64 + c] = s / fmaxf(cnt, 1.0f);
  }
}

// ---------------- Head: concat -> 2x Dense(128,relu, shared W) -> sigmoid ----------------

__global__ __launch_bounds__(512) void head_kernel(const float* __restrict__ p,
                                                   const float* __restrict__ Wd,
                                                   const float* __restrict__ bd,
                                                   const float* __restrict__ Wo,
                                                   const float* __restrict__ bo,
                                                   float* __restrict__ out) {
  __shared__ float cur[64][128];
  __shared__ float nxt[64][128];
  int tid = threadIdx.x;
  const float* p1 = p;
  const float* p2 = p + 64 * 64;
  for (int i = tid; i < 64 * 128; i += 512) {
    int r = i >> 7, c = i & 127;
    cur[r][c] = (c < 64) ? p1[r * 64 + c] : p2[r * 64 + (c - 64)];
  }
  __syncthreads();
  int c0 = (tid & 31) * 4;
  int r0 = (tid >> 5) * 4;
  for (int layer = 0; layer < 2; ++layer) {
    float acc[4][4] = {};
    #pragma unroll 4
    for (int k = 0; k < 128; ++k) {
      float4 w = *reinterpret_cast<const float4*>(&Wd[k * 128 + c0]);
      #pragma unroll
      for (int i = 0; i < 4; ++i) {
        float x = cur[r0 + i][k];
        acc[i][0] = fmaf(x, w.x, acc[i][0]);
        acc[i][1] = fmaf(x, w.y, acc[i][1]);
        acc[i][2] = fmaf(x, w.z, acc[i][2]);
        acc[i][3] = fmaf(x, w.w, acc[i][3]);
      }
    }
    float4 bv = *reinterpret_cast<const float4*>(&bd[c0]);
    __syncthreads();
    #pragma unroll
    for (int i = 0; i < 4; ++i) {
      float4 o;
      o.x = fmaxf(acc[i][0] + bv.x, 0.f);
      o.y = fmaxf(acc[i][1] + bv.y, 0.f);
      o.z = fmaxf(acc[i][2] + bv.z, 0.f);
      o.w = fmaxf(acc[i][3] + bv.w, 0.f);
      *reinterpret_cast<float4*>(&nxt[r0 + i][c0]) = o;
    }
    __syncthreads();
    for (int i = tid; i < 64 * 128; i += 512) (&cur[0][0])[i] = (&nxt[0][0])[i];
    __syncthreads();
  }
  int wv = tid >> 6, lane = tid & 63;
  for (int r = wv; r < 64; r += 8) {
    float v = cur[r][lane] * Wo[lane] + cur[r][64 + lane] * Wo[64 + lane];
    #pragma unroll
    for (int off = 32; off; off >>= 1) v += __shfl_down(v, off);
    if (lane == 0) out[r] = 1.0f / (1.0f + expf(-(v + bo[0])));
  }
}

// ---------------- launch ----------------

extern "C" void kernel_launch(void* const* d_in, const int* in_sizes, int n_in,
                              void* d_out, int out_size, void* d_ws, size_t ws_size,
                              hipStream_t stream) {
  const float* x1  = (const float*)d_in[0];
  const float* x2  = (const float*)d_in[1];
  const int* e1    = (const int*)d_in[2];
  const int* e2    = (const int*)d_in[3];
  const int* seg1  = (const int*)d_in[4];
  const int* seg2  = (const int*)d_in[5];
  const float* W1a = (const float*)d_in[6];  const float* b1a = (const float*)d_in[7];
  const float* g1a = (const float*)d_in[8];  const float* be1a = (const float*)d_in[9];
  const float* W1b = (const float*)d_in[10]; const float* b1b = (const float*)d_in[11];
  const float* g1b = (const float*)d_in[12]; const float* be1b = (const float*)d_in[13];
  const float* W2a = (const float*)d_in[14]; const float* b2a = (const float*)d_in[15];
  const float* g2a = (const float*)d_in[16]; const float* be2a = (const float*)d_in[17];
  const float* W2b = (const float*)d_in[18]; const float* b2b = (const float*)d_in[19];
  const float* g2b = (const float*)d_in[20]; const float* be2b = (const float*)d_in[21];
  const float* Wd  = (const float*)d_in[22]; const float* bd  = (const float*)d_in[23];
  const float* Wo  = (const float*)d_in[24]; const float* bo  = (const float*)d_in[25];
  float* out = (float*)d_out;

  const int N = in_sizes[0] / 128;
  const int E = in_sizes[2] / 2;

  char* ws = (char*)d_ws;
  size_t off = 0;
  auto alloc = [&](size_t bytes) -> void* {
    void* ptr = ws + off;
    off += (bytes + 255) & ~(size_t)255;
    return ptr;
  };
  float* h    = (float*)alloc((size_t)N * 128 * sizeof(float));
  float* aggb = (float*)alloc((size_t)N * 128 * sizeof(float));
  // int scratch: [counts 2N][cursor 2N][gcur 1] -> one memset
  int* counts = (int*)alloc((size_t)(4 * N + 1) * sizeof(int));
  int* cursor = counts + 2 * N;
  int* gcur   = counts + 4 * N;
  int* offs   = (int*)alloc((size_t)(2 * N) * sizeof(int));
  int* csr    = (int*)alloc((size_t)(2 * E) * sizeof(int));
  float* pbuf = (float*)alloc(2 * 64 * 64 * sizeof(float));
  (void)ws_size; (void)n_in; (void)out_size;

  // ---- CSR build for both branches up-front ----
  hipMemsetAsync(counts, 0, (size_t)(4 * N + 1) * sizeof(int), stream);
  {
    dim3 g((E + 255) / 256, 2);
    hist2_kernel<<<g, 256, 0, stream>>>(e1 + E, e2 + E, counts, E, N);
    alloc_kernel<<<(2 * N + 255) / 256, 256, 0, stream>>>(counts, offs, gcur, 2 * N);
    fill2_kernel<<<g, 256, 0, stream>>>(e1, e1 + E, e2, e2 + E, offs, cursor, csr, E, N);
  }

  struct Branch {
    const float *x; const int *seg;
    const float *Wa, *ba, *ga, *bea, *Wb, *bb, *gb, *beb;
  };
  Branch brs[2] = {
    {x1, seg1, W1a, b1a, g1a, be1a, W1b, b1b, g1b, be1b},
    {x2, seg2, W2a, b2a, g2a, be2a, W2b, b2b, g2b, be2b},
  };

  for (int b = 0; b < 2; ++b) {
    const int* offs_b = offs + b * N;
    const int* cnts_b = counts + b * N;
    gemm_kernel<128><<<(N + 63) / 64, 256, 0, stream>>>(brs[b].x, brs[b].Wa, brs[b].ba, h, N);
    agg_kernel<128><<<(N + 3) / 4, 256, 0, stream>>>(h, offs_b, cnts_b, csr, brs[b].ga, brs[b].bea, aggb, N);
    gemm_kernel<64><<<(N + 63) / 64, 256, 0, stream>>>(aggb, brs[b].Wb, brs[b].bb, h, N);
    agg_kernel<64><<<(N + 3) / 4, 256, 0, stream>>>(h, offs_b, cnts_b, csr, brs[b].gb, brs[b].beb, aggb, N);
    pool_kernel<<<64, 1024, 0, stream>>>(aggb, brs[b].seg, pbuf + b * 64 * 64, N);
  }
  head_kernel<<<1, 512, 0, stream>>>(pbuf, Wd, bd, Wo, bo, out);
}